// Round 2
// baseline (82.085 us; speedup 1.0000x reference)
//
#include <hip/hip_runtime.h>
#include <math.h>

// out[i, j] = -|| relu(lab[j, :] - vis[i, :]) ||_2
// lab: (512, 512) f32   vis: (1024, 512) f32   out: (1024, 512) f32

typedef float f32x4 __attribute__((ext_vector_type(4)));
typedef float f32x2 __attribute__((ext_vector_type(2)));

#define N_VIS  1024
#define M_LAB  512
#define DDIM   512
#define BK     128          // d's per chunk
#define NSPLIT 4            // DDIM / BK
#define SLICE  (N_VIS * M_LAB)
#define PADR   68           // row-dim pad (64 rows + 4): breaks pow2 strides

// -------- main: each block computes a 64x64 output tile's partial sum over 128 d's
// LDS layout is transposed: s[d][row], so compute reads 4 consecutive rows at
// fixed d with one ds_read_b128.
__global__ __launch_bounds__(256) void order_sim_main_f32(
    const float* __restrict__ lab, const float* __restrict__ vis,
    float* __restrict__ part) {
  __shared__ float sV[BK][PADR];   // vis tile, transposed
  __shared__ float sL[BK][PADR];   // lab tile, transposed

  const int bx = blockIdx.x;   // i-block (0..15)
  const int by = blockIdx.y;   // j-block (0..7)
  const int bz = blockIdx.z;   // d-chunk (0..3)
  const int t  = threadIdx.x;

  // ---- stage both tiles with transpose (float4 global read -> 4 scalar LDS writes)
  {
    const int row = t >> 2;            // 0..63
    const int c4  = t & 3;
    const float* vb = vis + (size_t)(bx * 64 + row) * DDIM + bz * BK;
    const float* lb = lab + (size_t)(by * 64 + row) * DDIM + bz * BK;
#pragma unroll
    for (int it = 0; it < 8; ++it) {
      const int d0 = (c4 + it * 4) * 4;      // 0..124 step 4
      f32x4 v = *(const f32x4*)(vb + d0);
      sV[d0 + 0][row] = v.x;
      sV[d0 + 1][row] = v.y;
      sV[d0 + 2][row] = v.z;
      sV[d0 + 3][row] = v.w;
      f32x4 l = *(const f32x4*)(lb + d0);
      sL[d0 + 0][row] = l.x;
      sL[d0 + 1][row] = l.y;
      sL[d0 + 2][row] = l.z;
      sL[d0 + 3][row] = l.w;
    }
  }
  __syncthreads();

  // ---- compute: 4x4 outputs per thread, d processed in pairs (f32x2 lanes)
  const int i0 = (t & 15) * 4;         // vis rows within tile
  const int j0 = (t >> 4) * 4;         // lab rows within tile
  f32x2 acc[4][4];
#pragma unroll
  for (int a = 0; a < 4; ++a)
#pragma unroll
    for (int b = 0; b < 4; ++b) acc[a][b] = (f32x2){0.0f, 0.0f};

  const f32x2 z2 = {0.0f, 0.0f};

#pragma unroll 4
  for (int k = 0; k < BK / 2; ++k) {   // k = pair of d's
    f32x4 a0 = *(const f32x4*)&sV[2 * k][i0];       // rows i0..i0+3 @ d=2k
    f32x4 a1 = *(const f32x4*)&sV[2 * k + 1][i0];   // rows i0..i0+3 @ d=2k+1
    f32x4 b0 = *(const f32x4*)&sL[2 * k][j0];
    f32x4 b1 = *(const f32x4*)&sL[2 * k + 1][j0];
#pragma unroll
    for (int ii = 0; ii < 4; ++ii) {
#pragma unroll
      for (int jj = 0; jj < 4; ++jj) {
        f32x2 d = {b0[jj] - a0[ii], b1[jj] - a1[ii]};
        d = __builtin_elementwise_max(d, z2);                 // relu
        acc[ii][jj] = __builtin_elementwise_fma(d, d, acc[ii][jj]);
      }
    }
  }

  // ---- write partial sums
  float* pw = part + (size_t)bz * SLICE;
#pragma unroll
  for (int ii = 0; ii < 4; ++ii) {
    f32x4 r = {acc[ii][0].x + acc[ii][0].y,
               acc[ii][1].x + acc[ii][1].y,
               acc[ii][2].x + acc[ii][2].y,
               acc[ii][3].x + acc[ii][3].y};
    *(f32x4*)(pw + (size_t)(bx * 64 + i0 + ii) * M_LAB + by * 64 + j0) = r;
  }
}

// -------- combine: out = -sqrt(p0+p1+p2+p3)
__global__ __launch_bounds__(256) void order_sim_combine(
    const float* __restrict__ part, float* __restrict__ out) {
  const size_t idx = ((size_t)blockIdx.x * 256 + threadIdx.x) * 4;
  f32x4 s = *(const f32x4*)(part + idx);
  s += *(const f32x4*)(part + SLICE + idx);
  s += *(const f32x4*)(part + 2 * (size_t)SLICE + idx);
  s += *(const f32x4*)(part + 3 * (size_t)SLICE + idx);
  f32x4 r;
  r.x = -sqrtf(s.x);
  r.y = -sqrtf(s.y);
  r.z = -sqrtf(s.z);
  r.w = -sqrtf(s.w);
  *(f32x4*)(out + idx) = r;
}

// -------- fallback if workspace is too small (correctness-only path)
__global__ __launch_bounds__(256) void order_sim_naive(
    const float* __restrict__ lab, const float* __restrict__ vis,
    float* __restrict__ out) {
  const int idx = blockIdx.x * 256 + threadIdx.x;   // over N*M
  const int i = idx >> 9;
  const int j = idx & 511;
  const float* v = vis + (size_t)i * DDIM;
  const float* l = lab + (size_t)j * DDIM;
  float s = 0.0f;
  for (int d = 0; d < DDIM; ++d) {
    float diff = l[d] - v[d];
    diff = fmaxf(diff, 0.0f);
    s = fmaf(diff, diff, s);
  }
  out[idx] = -sqrtf(s);
}

extern "C" void kernel_launch(void* const* d_in, const int* in_sizes, int n_in,
                              void* d_out, int out_size, void* d_ws, size_t ws_size,
                              hipStream_t stream) {
  // Defensive input-order detection: lab has 512*512 elements, vis 1024*512.
  const float* lab;
  const float* vis;
  if (in_sizes[0] == M_LAB * DDIM) {
    lab = (const float*)d_in[0];
    vis = (const float*)d_in[1];
  } else {
    vis = (const float*)d_in[0];
    lab = (const float*)d_in[1];
  }
  float* out = (float*)d_out;                  // (1024, 512)

  const size_t ws_needed = (size_t)NSPLIT * SLICE * sizeof(float);  // 8 MB
  if (ws_size >= ws_needed) {
    float* part = (float*)d_ws;
    dim3 grid(N_VIS / 64, M_LAB / 64, NSPLIT);   // 16 x 8 x 4 = 512 blocks
    order_sim_main_f32<<<grid, 256, 0, stream>>>(lab, vis, part);
    order_sim_combine<<<SLICE / (256 * 4), 256, 0, stream>>>(part, out);
  } else {
    order_sim_naive<<<(N_VIS * M_LAB) / 256, 256, 0, stream>>>(lab, vis, out);
  }
}

// Round 3
// 81.637 us; speedup vs baseline: 1.0055x; 1.0055x over previous
//
#include <hip/hip_runtime.h>
#include <math.h>

// out[i, j] = -|| relu(lab[j, :] - vis[i, :]) ||_2
// lab: (512, 512) f32   vis: (1024, 512) f32   out: (1024, 512) f32

typedef float f32x4 __attribute__((ext_vector_type(4)));
typedef float f32x2 __attribute__((ext_vector_type(2)));

#define N_VIS  1024
#define M_LAB  512
#define DDIM   512
#define BK     128          // d's per chunk (per-block K extent)
#define NSPLIT 4            // DDIM / BK
#define SLICE  (N_VIS * M_LAB)
#define PADR   68           // row-dim stride (64 rows + 4): 272B, 16B-aligned, pow2-free

// -------- main: each block computes a 64x64 output tile's partial sum over 128 d's
// LDS transposed: s[d][row]; compute reads 4 consecutive rows at fixed d per b128.
__global__ __launch_bounds__(256, 2) void order_sim_main_f32(
    const float* __restrict__ lab, const float* __restrict__ vis,
    float* __restrict__ part) {
  __shared__ float sV[BK][PADR];   // vis tile, transposed
  __shared__ float sL[BK][PADR];   // lab tile, transposed

  const int bx = blockIdx.x;   // i-block (0..15)
  const int by = blockIdx.y;   // j-block (0..7)
  const int bz = blockIdx.z;   // d-chunk (0..3)
  const int t  = threadIdx.x;

  // ---- stage both tiles with transpose (float4 global read -> 4 scalar LDS writes)
  {
    const int row = t >> 2;            // 0..63
    const int c4  = t & 3;
    const float* vb = vis + (size_t)(bx * 64 + row) * DDIM + bz * BK;
    const float* lb = lab + (size_t)(by * 64 + row) * DDIM + bz * BK;
#pragma unroll
    for (int it = 0; it < 8; ++it) {
      const int d0 = (c4 + it * 4) * 4;      // 0..124 step 4
      f32x4 v = *(const f32x4*)(vb + d0);
      sV[d0 + 0][row] = v.x;
      sV[d0 + 1][row] = v.y;
      sV[d0 + 2][row] = v.z;
      sV[d0 + 3][row] = v.w;
      f32x4 l = *(const f32x4*)(lb + d0);
      sL[d0 + 0][row] = l.x;
      sL[d0 + 1][row] = l.y;
      sL[d0 + 2][row] = l.z;
      sL[d0 + 3][row] = l.w;
    }
  }
  __syncthreads();

  // ---- compute: 4x4 outputs per thread, 4 d's per iteration, 2 independent chains
  const int i0 = (t & 15) * 4;         // vis rows within tile
  const int j0 = (t >> 4) * 4;         // lab rows within tile

  f32x2 accA[4][4];                    // chain A: d = 4k, 4k+1
  f32x2 accB[4][4];                    // chain B: d = 4k+2, 4k+3
#pragma unroll
  for (int a = 0; a < 4; ++a)
#pragma unroll
    for (int b = 0; b < 4; ++b) {
      accA[a][b] = (f32x2){0.0f, 0.0f};
      accB[a][b] = (f32x2){0.0f, 0.0f};
    }

  const f32x2 z2 = {0.0f, 0.0f};

#pragma unroll 2
  for (int k4 = 0; k4 < BK / 4; ++k4) {   // 32 iterations, 4 d's each
    const float* pv = &sV[4 * k4][0];
    const float* pl = &sL[4 * k4][0];
    f32x4 a0 = *(const f32x4*)(pv + 0 * PADR + i0);   // rows i0..i0+3 @ d=4k4
    f32x4 a1 = *(const f32x4*)(pv + 1 * PADR + i0);
    f32x4 a2 = *(const f32x4*)(pv + 2 * PADR + i0);
    f32x4 a3 = *(const f32x4*)(pv + 3 * PADR + i0);
    f32x4 b0 = *(const f32x4*)(pl + 0 * PADR + j0);
    f32x4 b1 = *(const f32x4*)(pl + 1 * PADR + j0);
    f32x4 b2 = *(const f32x4*)(pl + 2 * PADR + j0);
    f32x4 b3 = *(const f32x4*)(pl + 3 * PADR + j0);
#pragma unroll
    for (int ii = 0; ii < 4; ++ii) {
#pragma unroll
      for (int jj = 0; jj < 4; ++jj) {
        f32x2 dA = {b0[jj] - a0[ii], b1[jj] - a1[ii]};
        dA = __builtin_elementwise_max(dA, z2);
        accA[ii][jj] = __builtin_elementwise_fma(dA, dA, accA[ii][jj]);
        f32x2 dB = {b2[jj] - a2[ii], b3[jj] - a3[ii]};
        dB = __builtin_elementwise_max(dB, z2);
        accB[ii][jj] = __builtin_elementwise_fma(dB, dB, accB[ii][jj]);
      }
    }
  }

  // ---- write partial sums
  float* pw = part + (size_t)bz * SLICE;
#pragma unroll
  for (int ii = 0; ii < 4; ++ii) {
    f32x4 r;
#pragma unroll
    for (int jj = 0; jj < 4; ++jj) {
      f32x2 s = accA[ii][jj] + accB[ii][jj];
      r[jj] = s.x + s.y;
    }
    *(f32x4*)(pw + (size_t)(bx * 64 + i0 + ii) * M_LAB + by * 64 + j0) = r;
  }
}

// -------- combine: out = -sqrt(p0+p1+p2+p3)
__global__ __launch_bounds__(256) void order_sim_combine(
    const float* __restrict__ part, float* __restrict__ out) {
  const size_t idx = ((size_t)blockIdx.x * 256 + threadIdx.x) * 4;
  f32x4 s = *(const f32x4*)(part + idx);
  s += *(const f32x4*)(part + SLICE + idx);
  s += *(const f32x4*)(part + 2 * (size_t)SLICE + idx);
  s += *(const f32x4*)(part + 3 * (size_t)SLICE + idx);
  f32x4 r;
  r.x = -sqrtf(s.x);
  r.y = -sqrtf(s.y);
  r.z = -sqrtf(s.z);
  r.w = -sqrtf(s.w);
  *(f32x4*)(out + idx) = r;
}

// -------- fallback if workspace is too small (correctness-only path)
__global__ __launch_bounds__(256) void order_sim_naive(
    const float* __restrict__ lab, const float* __restrict__ vis,
    float* __restrict__ out) {
  const int idx = blockIdx.x * 256 + threadIdx.x;   // over N*M
  const int i = idx >> 9;
  const int j = idx & 511;
  const float* v = vis + (size_t)i * DDIM;
  const float* l = lab + (size_t)j * DDIM;
  float s = 0.0f;
  for (int d = 0; d < DDIM; ++d) {
    float diff = l[d] - v[d];
    diff = fmaxf(diff, 0.0f);
    s = fmaf(diff, diff, s);
  }
  out[idx] = -sqrtf(s);
}

extern "C" void kernel_launch(void* const* d_in, const int* in_sizes, int n_in,
                              void* d_out, int out_size, void* d_ws, size_t ws_size,
                              hipStream_t stream) {
  // Defensive input-order detection: lab has 512*512 elements, vis 1024*512.
  const float* lab;
  const float* vis;
  if (in_sizes[0] == M_LAB * DDIM) {
    lab = (const float*)d_in[0];
    vis = (const float*)d_in[1];
  } else {
    vis = (const float*)d_in[0];
    lab = (const float*)d_in[1];
  }
  float* out = (float*)d_out;                  // (1024, 512)

  const size_t ws_needed = (size_t)NSPLIT * SLICE * sizeof(float);  // 8 MB
  if (ws_size >= ws_needed) {
    float* part = (float*)d_ws;
    dim3 grid(N_VIS / 64, M_LAB / 64, NSPLIT);   // 16 x 8 x 4 = 512 blocks
    order_sim_main_f32<<<grid, 256, 0, stream>>>(lab, vis, part);
    order_sim_combine<<<SLICE / (256 * 4), 256, 0, stream>>>(part, out);
  } else {
    order_sim_naive<<<(N_VIS * M_LAB) / 256, 256, 0, stream>>>(lab, vis, out);
  }
}

// Round 4
// 79.813 us; speedup vs baseline: 1.0285x; 1.0229x over previous
//
#include <hip/hip_runtime.h>
#include <math.h>

// out[i, j] = -|| relu(lab[j, :] - vis[i, :]) ||_2
// lab: (512, 512) f32   vis: (1024, 512) f32   out: (1024, 512) f32

typedef float f32x4 __attribute__((ext_vector_type(4)));
typedef float f32x2 __attribute__((ext_vector_type(2)));

#define N_VIS  1024
#define M_LAB  512
#define DDIM   512
#define BK     128          // d's per chunk (per-block K extent)
#define NSPLIT 4            // DDIM / BK
#define SLICE  (N_VIS * M_LAB)
#define SURD   66           // row-array stride in f32x2 units (528B, 16B-multiple)

// -------- main: 64x64 output tile partial sums over 128 d's per block.
// LDS layout: d-PAIRED and transposed: s[k][row] = {x[row][2k], x[row][2k+1]}
// so each b128 read yields 2 rows x (2 d's) and pk_sub/pk_fma operands are
// naturally adjacent register pairs (no v_pk_max_f32 exists; max scalarizes).
__global__ __launch_bounds__(256, 2) void order_sim_main_f32(
    const float* __restrict__ lab, const float* __restrict__ vis,
    float* __restrict__ part) {
  __shared__ f32x2 sV[64 * SURD];   // 33,792 B
  __shared__ f32x2 sL[64 * SURD];   // 33,792 B

  const int bx = blockIdx.x;   // i-block (0..15)
  const int by = blockIdx.y;   // j-block (0..7)
  const int bz = blockIdx.z;   // d-chunk (0..3)
  const int t  = threadIdx.x;

  // ---- stage both tiles (float4 global read -> 2 ds_write_b64, d-paired)
  {
    const int row = t >> 2;            // 0..63
    const int c4  = t & 3;
    const float* vb = vis + (size_t)(bx * 64 + row) * DDIM + bz * BK;
    const float* lb = lab + (size_t)(by * 64 + row) * DDIM + bz * BK;
#pragma unroll
    for (int it = 0; it < 8; ++it) {
      const int f4 = c4 + it * 4;      // float4 index 0..31 (covers d = 4*f4..4*f4+3)
      const int k0 = f4 * 2;           // d-pair index
      f32x4 v = *(const f32x4*)(vb + f4 * 4);
      sV[k0 * SURD + row]       = (f32x2){v.x, v.y};
      sV[(k0 + 1) * SURD + row] = (f32x2){v.z, v.w};
      f32x4 l = *(const f32x4*)(lb + f4 * 4);
      sL[k0 * SURD + row]       = (f32x2){l.x, l.y};
      sL[(k0 + 1) * SURD + row] = (f32x2){l.z, l.w};
    }
  }
  __syncthreads();

  // ---- compute: 4x4 outputs per thread, one d-pair per k iteration
  const int i0 = (t & 15) * 4;         // vis rows within tile
  const int j0 = (t >> 4) * 4;         // lab rows within tile

  f32x2 acc[4][4];
#pragma unroll
  for (int a = 0; a < 4; ++a)
#pragma unroll
    for (int b = 0; b < 4; ++b) acc[a][b] = (f32x2){0.0f, 0.0f};

  const f32x2 z2 = {0.0f, 0.0f};

#pragma unroll 4
  for (int k = 0; k < BK / 2; ++k) {   // 64 iterations, one d-pair each
    const f32x2* pv = sV + k * SURD;
    const f32x2* pl = sL + k * SURD;
    f32x4 aA = *(const f32x4*)(pv + i0);       // rows i0, i0+1 ({d0,d1} each)
    f32x4 aB = *(const f32x4*)(pv + i0 + 2);   // rows i0+2, i0+3
    f32x4 bA = *(const f32x4*)(pl + j0);
    f32x4 bB = *(const f32x4*)(pl + j0 + 2);
    f32x2 a[4], b[4];
    a[0] = (f32x2){aA.x, aA.y};
    a[1] = (f32x2){aA.z, aA.w};
    a[2] = (f32x2){aB.x, aB.y};
    a[3] = (f32x2){aB.z, aB.w};
    b[0] = (f32x2){bA.x, bA.y};
    b[1] = (f32x2){bA.z, bA.w};
    b[2] = (f32x2){bB.x, bB.y};
    b[3] = (f32x2){bB.z, bB.w};
#pragma unroll
    for (int ii = 0; ii < 4; ++ii) {
#pragma unroll
      for (int jj = 0; jj < 4; ++jj) {
        f32x2 d = b[jj] - a[ii];                       // v_pk_add_f32 (neg mod)
        d = __builtin_elementwise_max(d, z2);          // 2x v_max_f32
        acc[ii][jj] = __builtin_elementwise_fma(d, d, acc[ii][jj]);  // v_pk_fma_f32
      }
    }
  }

  // ---- write partial sums
  float* pw = part + (size_t)bz * SLICE;
#pragma unroll
  for (int ii = 0; ii < 4; ++ii) {
    f32x4 r;
#pragma unroll
    for (int jj = 0; jj < 4; ++jj) {
      f32x2 s = acc[ii][jj];
      r[jj] = s.x + s.y;
    }
    *(f32x4*)(pw + (size_t)(bx * 64 + i0 + ii) * M_LAB + by * 64 + j0) = r;
  }
}

// -------- combine: out = -sqrt(p0+p1+p2+p3)
__global__ __launch_bounds__(256) void order_sim_combine(
    const float* __restrict__ part, float* __restrict__ out) {
  const size_t idx = ((size_t)blockIdx.x * 256 + threadIdx.x) * 4;
  f32x4 s = *(const f32x4*)(part + idx);
  s += *(const f32x4*)(part + SLICE + idx);
  s += *(const f32x4*)(part + 2 * (size_t)SLICE + idx);
  s += *(const f32x4*)(part + 3 * (size_t)SLICE + idx);
  f32x4 r;
  r.x = -sqrtf(s.x);
  r.y = -sqrtf(s.y);
  r.z = -sqrtf(s.z);
  r.w = -sqrtf(s.w);
  *(f32x4*)(out + idx) = r;
}

// -------- fallback if workspace is too small (correctness-only path)
__global__ __launch_bounds__(256) void order_sim_naive(
    const float* __restrict__ lab, const float* __restrict__ vis,
    float* __restrict__ out) {
  const int idx = blockIdx.x * 256 + threadIdx.x;   // over N*M
  const int i = idx >> 9;
  const int j = idx & 511;
  const float* v = vis + (size_t)i * DDIM;
  const float* l = lab + (size_t)j * DDIM;
  float s = 0.0f;
  for (int d = 0; d < DDIM; ++d) {
    float diff = l[d] - v[d];
    diff = fmaxf(diff, 0.0f);
    s = fmaf(diff, diff, s);
  }
  out[idx] = -sqrtf(s);
}

extern "C" void kernel_launch(void* const* d_in, const int* in_sizes, int n_in,
                              void* d_out, int out_size, void* d_ws, size_t ws_size,
                              hipStream_t stream) {
  // Defensive input-order detection: lab has 512*512 elements, vis 1024*512.
  const float* lab;
  const float* vis;
  if (in_sizes[0] == M_LAB * DDIM) {
    lab = (const float*)d_in[0];
    vis = (const float*)d_in[1];
  } else {
    vis = (const float*)d_in[0];
    lab = (const float*)d_in[1];
  }
  float* out = (float*)d_out;                  // (1024, 512)

  const size_t ws_needed = (size_t)NSPLIT * SLICE * sizeof(float);  // 8 MB
  if (ws_size >= ws_needed) {
    float* part = (float*)d_ws;
    dim3 grid(N_VIS / 64, M_LAB / 64, NSPLIT);   // 16 x 8 x 4 = 512 blocks
    order_sim_main_f32<<<grid, 256, 0, stream>>>(lab, vis, part);
    order_sim_combine<<<SLICE / (256 * 4), 256, 0, stream>>>(part, out);
  } else {
    order_sim_naive<<<(N_VIS * M_LAB) / 256, 256, 0, stream>>>(lab, vis, out);
  }
}

// Round 7
// 77.181 us; speedup vs baseline: 1.0635x; 1.0341x over previous
//
#include <hip/hip_runtime.h>
#include <math.h>

// out[i, j] = -|| relu(lab[j, :] - vis[i, :]) ||_2
// lab: (512, 512) f32   vis: (1024, 512) f32   out: (1024, 512) f32
//
// FP16/BF16 intermediates are ruled out empirically: three algebraically
// equivalent fp16 formulations all produced absmax 8.25 (>> 0.56 threshold);
// since max(l,v)-v == relu(l-v) bit-exactly in fp16, that IS the fp16
// precision on this data, not a miscompile. f32 compute only.
//
// Fully fused single kernel (no workspace): 32x32 output tile per block,
// K=512 processed as 4 chunks of 128 through double-role LDS buffers,
// -sqrt applied in epilogue. Saves the 8MB+8MB part round-trip and the
// second kernel launch vs the split-K version (round 4, 79.8 us).

typedef float f32x4 __attribute__((ext_vector_type(4)));
typedef float f32x2 __attribute__((ext_vector_type(2)));

#define N_VIS 1024
#define M_LAB 512
#define DDIM  512
#define BK    128          // d's per staged chunk
#define NCH   4            // DDIM / BK
#define TI    32           // vis rows per block tile
#define TJ    32           // lab rows per block tile
#define SURD  34           // row stride in f32x2 units (272B: 16B-multiple, pow2-free)

// grid (32, 16) = 512 blocks (2 per CU, 8 waves/CU), 256 threads.
__global__ __launch_bounds__(256, 2) void order_sim_fused(
    const float* __restrict__ lab, const float* __restrict__ vis,
    float* __restrict__ out) {
  // LDS: d-PAIRED, transposed: s[k][row] = {x[row][2k], x[row][2k+1]},
  // so pk_add/pk_fma operands are adjacent register pairs.
  __shared__ f32x2 sV[64 * SURD];   // 17.4 KB
  __shared__ f32x2 sL[64 * SURD];   // 17.4 KB

  const int bx = blockIdx.x;   // i-tile (0..31)
  const int by = blockIdx.y;   // j-tile (0..15)
  const int t  = threadIdx.x;

  // compute assignment: 2x2 outputs per thread
  const int i0 = (t & 15) * 2;       // vis rows within tile (even)
  const int j0 = (t >> 4) * 2;       // lab rows within tile (even)

  // staging assignment: 32 rows x 128 d per tensor by 256 threads
  const int srow = t >> 3;           // 0..31
  const int sc8  = t & 7;            // 0..7

  f32x2 acc[2][2];
#pragma unroll
  for (int a = 0; a < 2; ++a)
#pragma unroll
    for (int b = 0; b < 2; ++b) acc[a][b] = (f32x2){0.0f, 0.0f};

  const f32x2 z2 = {0.0f, 0.0f};

  const float* vbase = vis + (size_t)(bx * TI + srow) * DDIM;
  const float* lbase = lab + (size_t)(by * TJ + srow) * DDIM;

#pragma unroll 1
  for (int ch = 0; ch < NCH; ++ch) {
    if (ch) __syncthreads();         // WAR: previous compute done before overwrite

    // ---- stage chunk ch (float4 global read -> 2 ds_write_b64, d-paired)
    const float* vb = vbase + ch * BK;
    const float* lb = lbase + ch * BK;
#pragma unroll
    for (int it = 0; it < 4; ++it) {
      const int f4 = sc8 + it * 8;   // float4 index 0..31 (d = 4*f4..4*f4+3)
      const int k0 = f4 * 2;         // d-pair index
      f32x4 v = *(const f32x4*)(vb + f4 * 4);
      sV[k0 * SURD + srow]       = (f32x2){v.x, v.y};
      sV[(k0 + 1) * SURD + srow] = (f32x2){v.z, v.w};
      f32x4 l = *(const f32x4*)(lb + f4 * 4);
      sL[k0 * SURD + srow]       = (f32x2){l.x, l.y};
      sL[(k0 + 1) * SURD + srow] = (f32x2){l.z, l.w};
    }
    __syncthreads();

    // ---- compute: 2x2 outputs, one d-pair per k iteration
#pragma unroll 8
    for (int k = 0; k < BK / 2; ++k) {
      f32x4 araw = *(const f32x4*)&sV[k * SURD + i0];   // rows i0, i0+1
      f32x4 braw = *(const f32x4*)&sL[k * SURD + j0];   // rows j0, j0+1
      f32x2 a0 = {araw.x, araw.y};
      f32x2 a1 = {araw.z, araw.w};
      f32x2 b0 = {braw.x, braw.y};
      f32x2 b1 = {braw.z, braw.w};

      f32x2 d;
      d = b0 - a0; d = __builtin_elementwise_max(d, z2);
      acc[0][0] = __builtin_elementwise_fma(d, d, acc[0][0]);
      d = b1 - a0; d = __builtin_elementwise_max(d, z2);
      acc[0][1] = __builtin_elementwise_fma(d, d, acc[0][1]);
      d = b0 - a1; d = __builtin_elementwise_max(d, z2);
      acc[1][0] = __builtin_elementwise_fma(d, d, acc[1][0]);
      d = b1 - a1; d = __builtin_elementwise_max(d, z2);
      acc[1][1] = __builtin_elementwise_fma(d, d, acc[1][1]);
    }
  }

  // ---- epilogue: out = -sqrt(sum), f32x2 store per output row
#pragma unroll
  for (int ii = 0; ii < 2; ++ii) {
    f32x2 r;
    r.x = -sqrtf(acc[ii][0].x + acc[ii][0].y);
    r.y = -sqrtf(acc[ii][1].x + acc[ii][1].y);
    *(f32x2*)(out + (size_t)(bx * TI + i0 + ii) * M_LAB + by * TJ + j0) = r;
  }
}

extern "C" void kernel_launch(void* const* d_in, const int* in_sizes, int n_in,
                              void* d_out, int out_size, void* d_ws, size_t ws_size,
                              hipStream_t stream) {
  // Size-based input detection (lab = 512*512 elements, vis = 1024*512).
  const float* lab;
  const float* vis;
  if (in_sizes[0] == M_LAB * DDIM) {
    lab = (const float*)d_in[0];
    vis = (const float*)d_in[1];
  } else {
    vis = (const float*)d_in[0];
    lab = (const float*)d_in[1];
  }
  float* out = (float*)d_out;                  // (1024, 512)

  dim3 grid(N_VIS / TI, M_LAB / TJ);           // 32 x 16 = 512 blocks
  order_sim_fused<<<grid, 256, 0, stream>>>(lab, vis, out);
  (void)d_ws; (void)ws_size; (void)n_in; (void)out_size;
}